// Round 9
// baseline (563.551 us; speedup 1.0000x reference)
//
#include <hip/hip_runtime.h>
#include <cstdint>

// Problem constants
#define NN 8192
#define FF 512
#define FO 64
#define NH 8
#define LDYE 520     // Y row stride: 512 numerator cols + 8 denom cols
#define YPART (8192 * 520)
#define SPLITK 2

// Tiled fp8 layouts (k-major 16-byte granules, staging order):
//  Ab: granule G = (rt*512 + k16)*128 + row
//  Vt: granule H = k16*640 + vrow   (vrow: h*64+o; 512+h = e-row; >=520 junk)

typedef __attribute__((ext_vector_type(8))) __bf16 bf16x8;
typedef __attribute__((ext_vector_type(4))) float f32x4;

__device__ __forceinline__ unsigned short f2bf(float f) {
    unsigned int u = __float_as_uint(f);
    u += 0x7fffu + ((u >> 16) & 1u);
    return (unsigned short)(u >> 16);
}

__device__ __forceinline__ void gload16(const void* g, void* l) {
    __builtin_amdgcn_global_load_lds(
        (const __attribute__((address_space(1))) unsigned int*)g,
        (__attribute__((address_space(3))) unsigned int*)l,
        16, 0, 0);
}

// ---------------------------------------------------------------------------
// K0: A fp32 {0.0,1.0} -> fp8 e4m3 (0x00/0x38, exact), tiled layout,
// coalesced writes (linear gid->granule).
// ---------------------------------------------------------------------------
__global__ __launch_bounds__(256) void k_convA8(const float* __restrict__ A,
                                                unsigned char* __restrict__ Ab) {
    const size_t gid = (size_t)blockIdx.x * 256 + threadIdx.x;
    const int row127 = (int)(gid & 127);
    const int k16 = (int)((gid >> 7) & 511);
    const int rt = (int)(gid >> 16);
    const uint4* src = (const uint4*)(A + (((size_t)(rt * 128 + row127)) << 13) + k16 * 16);
    uint4 f0 = src[0], f1 = src[1], f2 = src[2], f3 = src[3];
#define PK8(v) (((v.x >> 22) & 0x38u) | (((v.y >> 22) & 0x38u) << 8) | \
                (((v.z >> 22) & 0x38u) << 16) | (((v.w >> 22) & 0x38u) << 24))
    uint4 o = {PK8(f0), PK8(f1), PK8(f2), PK8(f3)};
#undef PK8
    *(uint4*)(Ab + (gid << 4)) = o;
}

// ---------------------------------------------------------------------------
// K0b: X fp32->bf16; kernels (h,f,o)->Kt (h,o,f) bf16.
// ---------------------------------------------------------------------------
__global__ __launch_bounds__(256) void k_prep(const float* __restrict__ X,
                                              const float* __restrict__ Kw,
                                              unsigned short* __restrict__ Xb,
                                              unsigned short* __restrict__ Ktb) {
    const int b = blockIdx.x;
    const int t = threadIdx.x;
    if (b < 2048) {
        size_t base = ((size_t)b * 256 + t) * 8;
        float4 a = *(const float4*)(X + base);
        float4 c = *(const float4*)(X + base + 4);
        ushort4 o0, o1;
        o0.x = f2bf(a.x); o0.y = f2bf(a.y); o0.z = f2bf(a.z); o0.w = f2bf(a.w);
        o1.x = f2bf(c.x); o1.y = f2bf(c.y); o1.z = f2bf(c.z); o1.w = f2bf(c.w);
        *(ushort4*)(Xb + base) = o0;
        *(ushort4*)(Xb + base + 4) = o1;
    } else {
        int h = b - 2048;
        for (int e = t; e < FF * FO; e += 256) {
            int o = e >> 9, f = e & 511;
            Ktb[(size_t)h * FF * FO + e] = f2bf(Kw[(size_t)h * FF * FO + (size_t)f * FO + o]);
        }
    }
}

// ---------------------------------------------------------------------------
// K1: WX = Xb @ Kt^T bf16 MFMA (K=512), s2 via shfl_xor, e = exp(s2),
// emit fp8 V into tiled Vt.  (Unchanged from R7.)
// ---------------------------------------------------------------------------
union WxSmem {
    struct { unsigned short Xs[4096]; unsigned short Ks[2048]; } s;
    unsigned char Vs[64][144];
};

__global__ __launch_bounds__(256) void k_wx(const unsigned short* __restrict__ Xb,
                                            const unsigned short* __restrict__ Ktb,
                                            const float* __restrict__ Aw,
                                            unsigned char* __restrict__ Vt) {
    __shared__ WxSmem sm;
    const int t = threadIdx.x;
    const int n0 = blockIdx.x * 128;
    const int h = blockIdx.y;
    const int lane = t & 63, w = t >> 6;
    const int quad = lane >> 4, l15 = lane & 15;

    const unsigned short* xS0 = Xb + (size_t)(n0 + (t & 127)) * FF + (t >> 7) * 8;
    const unsigned short* xS1 = Xb + (size_t)(n0 + ((t + 256) & 127)) * FF + ((t + 256) >> 7) * 8;
    unsigned short* xD0 = sm.s.Xs + t * 8;
    unsigned short* xD1 = sm.s.Xs + (t + 256) * 8;
    const unsigned short* kS = Ktb + (size_t)h * FF * FO + (size_t)(t & 63) * FF + (t >> 6) * 8;
    unsigned short* kD = sm.s.Ks + t * 8;

    const bf16x8* aF[2];
    const bf16x8* bF[4];
    for (int i = 0; i < 2; ++i)
        aF[i] = (const bf16x8*)(sm.s.Xs + (size_t)(quad * 128 + w * 32 + i * 16 + l15) * 8);
    for (int j = 0; j < 4; ++j)
        bF[j] = (const bf16x8*)(sm.s.Ks + (size_t)(quad * 64 + j * 16 + l15) * 8);

    f32x4 acc[2][4] = {};
    for (int f0 = 0; f0 < FF; f0 += 32) {
        gload16(xS0 + f0, xD0);
        gload16(xS1 + f0, xD1);
        gload16(kS + f0, kD);
        __syncthreads();
        bf16x8 av[2], bv[4];
        for (int i = 0; i < 2; ++i) av[i] = aF[i][0];
        for (int j = 0; j < 4; ++j) bv[j] = bF[j][0];
        for (int i = 0; i < 2; ++i)
            for (int j = 0; j < 4; ++j)
                acc[i][j] = __builtin_amdgcn_mfma_f32_16x16x32_bf16(av[i], bv[j], acc[i][j], 0, 0, 0);
        __syncthreads();
    }

    float a2v[4];
    for (int j = 0; j < 4; ++j) a2v[j] = Aw[h * 128 + 64 + j * 16 + l15];
    float ex[2][4];
    for (int i = 0; i < 2; ++i)
        for (int r = 0; r < 4; ++r) {
            float p = acc[i][0][r] * a2v[0] + acc[i][1][r] * a2v[1]
                    + acc[i][2][r] * a2v[2] + acc[i][3][r] * a2v[3];
            p += __shfl_xor(p, 1);
            p += __shfl_xor(p, 2);
            p += __shfl_xor(p, 4);
            p += __shfl_xor(p, 8);
            ex[i][r] = __expf(p);
        }

    for (int i = 0; i < 2; ++i)
        for (int j = 0; j < 4; ++j) {
            int rowb = w * 32 + i * 16 + quad * 4;
            int col = j * 16 + l15;
            unsigned u = __builtin_amdgcn_cvt_pk_fp8_f32(
                ex[i][0] * acc[i][j][0], ex[i][1] * acc[i][j][1], 0, false);
            u = __builtin_amdgcn_cvt_pk_fp8_f32(
                ex[i][2] * acc[i][j][2], ex[i][3] * acc[i][j][3], (int)u, true);
            *(unsigned*)&sm.Vs[col][rowb] = u;
        }
    __syncthreads();
    for (int j2 = 0; j2 < 2; ++j2) {
        int vid = t + j2 * 256;            // 0..511 = 64 o x 8 k16o (uint4)
        int o = vid >> 3, k16o = vid & 7;
        size_t H = (size_t)((n0 >> 4) + k16o) * 640 + h * 64 + o;
        *(uint4*)(Vt + (H << 4)) = *(const uint4*)&sm.Vs[o][k16o * 16];
    }
    if (l15 == 0) {
        for (int i = 0; i < 2; ++i)
            for (int r = 0; r < 4; ++r) {
                int row = w * 32 + i * 16 + quad * 4 + r;
                unsigned u = __builtin_amdgcn_cvt_pk_fp8_f32(ex[i][r], ex[i][r], 0, false);
                size_t H = (size_t)((n0 >> 4) + (row >> 4)) * 640 + 512 + h;
                Vt[(H << 4) + (row & 15)] = (unsigned char)(u & 0xff);
            }
    }
}

// ---------------------------------------------------------------------------
// K2 (R9): PRODUCER-CONSUMER wave specialization.
// BM=128, BN=80, BK=64; waves 0-1 = consumers (64x80 tile each, 40 MFMA/iter),
// wave 2 stages A (8x 1KB bursts), wave 3 stages B (5x 1KB). Double-buffered
// 26 KB LDS. The vmcnt drain before s_barrier is PER-WAVE: producers' drain
// overlaps consumers' MFMA+ds_read -- the overlap a single-wave 2-barrier
// loop cannot express (R8 showed same-wave prefetch just moves the drain).
// ct=7 covers the 520 useful V rows; SPLITK=2 -> grid 896.
// XCD swizzle: the 7 ct-friends of each (rt,part) share one XCD.
// ---------------------------------------------------------------------------
__global__ __launch_bounds__(256) void k_gemm(const unsigned char* __restrict__ Ab,
                                              const unsigned char* __restrict__ Vt,
                                              float* __restrict__ Y) {
    __shared__ unsigned char As0[8192], As1[8192];   // kq(4) x row(128) x 16 B
    __shared__ unsigned char Bs0[5120], Bs1[5120];   // kq(4) x n(80)  x 16 B
    const int t = threadIdx.x;
    const int id = blockIdx.x;
    const int xcd = id & 7;
    const int u = id >> 3;        // 0..111
    const int ct = u % 7;         // 0..6
    const int gq = u / 7;         // 0..15
    const int rp = gq * 8 + xcd;  // 0..127
    const int rt = rp & 63;
    const int part = rp >> 6;     // 0..1
    const int ks0 = part * 64;    // 128 iters of BK=64 total, split in 2
    const int ks1 = ks0 + 64;

    const int lane = t & 63;
    const int w = t >> 6;
    const int quad = lane >> 4, l15 = lane & 15;

    // producer source bases (within-iter constant offsets)
    const unsigned char* aBase = Ab + ((size_t)rt << 20);
    int bsrc[5];                  // B granule g = r*64+lane -> source offset
    for (int r = 0; r < 5; ++r) {
        int g = r * 64 + lane;
        bsrc[r] = (g / 80) * 10240 + (ct * 80 + g % 80) * 16;
    }

    // consumer fragment offsets (h2=0 half; h2=1 adds 4096 / 2560)
    int aOff[4], bOff[5];
    for (int i = 0; i < 4; ++i)
        aOff[i] = (quad >> 1) * 2048 + (quad & 1) * 8 + (w * 64 + i * 16 + l15) * 16;
    for (int j = 0; j < 5; ++j)
        bOff[j] = (quad >> 1) * 1280 + (quad & 1) * 8 + (j * 16 + l15) * 16;

    f32x4 acc[4][5] = {};

#define STAGE_A(ks, AD)                                                        \
    do {                                                                       \
        const unsigned char* s = aBase + ((size_t)(ks) << 13) + lane * 16;     \
        _Pragma("unroll")                                                      \
        for (int r = 0; r < 8; ++r)                                            \
            gload16(s + r * 1024, (AD) + (r * 64 + lane) * 16);                \
    } while (0)

#define STAGE_B(ks, BD)                                                        \
    do {                                                                       \
        const unsigned char* s = Vt + (size_t)(ks) * 40960;                    \
        _Pragma("unroll")                                                      \
        for (int r = 0; r < 5; ++r)                                            \
            gload16(s + bsrc[r], (BD) + (r * 64 + lane) * 16);                 \
    } while (0)

#define MFMA_TILE(AS, BS)                                                      \
    do {                                                                       \
        _Pragma("unroll")                                                      \
        for (int h2 = 0; h2 < 2; ++h2) {                                       \
            long long av[4], bv[5];                                            \
            for (int i = 0; i < 4; ++i)                                        \
                av[i] = *(const long long*)((AS) + aOff[i] + h2 * 4096);       \
            for (int j = 0; j < 5; ++j)                                        \
                bv[j] = *(const long long*)((BS) + bOff[j] + h2 * 2560);       \
            for (int i = 0; i < 4; ++i)                                        \
                for (int j = 0; j < 5; ++j)                                    \
                    acc[i][j] = __builtin_amdgcn_mfma_f32_16x16x32_fp8_fp8(    \
                        av[i], bv[j], acc[i][j], 0, 0, 0);                     \
        }                                                                      \
    } while (0)

    if (w == 2) STAGE_A(ks0, As0);
    else if (w == 3) STAGE_B(ks0, Bs0);
    __syncthreads();
    int p = 0;
    for (int ks = ks0; ks < ks1; ++ks) {
        if (p == 0) {
            if (w < 2) MFMA_TILE(As0, Bs0);
            else if (ks + 1 < ks1) {
                if (w == 2) STAGE_A(ks + 1, As1);
                else STAGE_B(ks + 1, Bs1);
            }
        } else {
            if (w < 2) MFMA_TILE(As1, Bs1);
            else if (ks + 1 < ks1) {
                if (w == 2) STAGE_A(ks + 1, As0);
                else STAGE_B(ks + 1, Bs0);
            }
        }
        __syncthreads();
        p ^= 1;
    }
#undef STAGE_A
#undef STAGE_B
#undef MFMA_TILE

    // C/D layout: col = lane&15, row = (lane>>4)*4 + reg. Consumers only.
    if (w < 2) {
        float* Yp = Y + (size_t)part * YPART;
        for (int i = 0; i < 4; ++i) {
            int row = rt * 128 + w * 64 + i * 16 + quad * 4;
            for (int j = 0; j < 5; ++j) {
                int col = ct * 80 + j * 16 + l15;
                if (col < 520) {
                    for (int r = 0; r < 4; ++r)
                        Yp[(size_t)(row + r) * LDYE + col] = acc[i][j][r];
                }
            }
        }
    }
}

// ---------------------------------------------------------------------------
// K3: out[n, h*64+o] = relu( sum_p Ynum / sum_p Yden )
// ---------------------------------------------------------------------------
__global__ __launch_bounds__(256) void k_epi(const float* __restrict__ Y,
                                             float* __restrict__ out) {
    int idx = blockIdx.x * 256 + threadIdx.x;
    int n = idx >> 7;
    int c = (idx & 127) * 4;
    int h = c >> 6;
    float4 u = {0.f, 0.f, 0.f, 0.f};
    float den = 0.f;
    const float* yp = Y + (size_t)n * LDYE;
#pragma unroll
    for (int p = 0; p < SPLITK; ++p) {
        float4 v = *(const float4*)(yp + c);
        u.x += v.x; u.y += v.y; u.z += v.z; u.w += v.w;
        den += yp[512 + h];
        yp += (size_t)YPART;
    }
    float inv = 1.0f / den;
    float4 o;
    o.x = fmaxf(u.x * inv, 0.f);
    o.y = fmaxf(u.y * inv, 0.f);
    o.z = fmaxf(u.z * inv, 0.f);
    o.w = fmaxf(u.w * inv, 0.f);
    *(float4*)(out + (size_t)n * 512 + c) = o;
}

extern "C" void kernel_launch(void* const* d_in, const int* in_sizes, int n_in,
                              void* d_out, int out_size, void* d_ws, size_t ws_size,
                              hipStream_t stream) {
    const float* X  = (const float*)d_in[0];   // (8192, 512)
    const float* A  = (const float*)d_in[1];   // (8192, 8192)
    const float* Kw = (const float*)d_in[2];   // (8, 512, 64)
    const float* Aw = (const float*)d_in[3];   // (8, 128)
    float* out = (float*)d_out;                // (8192, 512)
    char* ws = (char*)d_ws;
    // ws: Ab 64 MiB | Vt 5 MiB | Yb 2*16.25 MiB (~101.5 MiB).
    // Xb (8 MiB) + Ktb (0.5 MiB) alias the head of Yb (consumed by k_wx
    // before k_gemm writes Yb).
    unsigned char* Ab = (unsigned char*)ws;
    unsigned char* Vt = (unsigned char*)(ws + (size_t)67108864);
    float* Yb = (float*)(ws + (size_t)67108864 + (size_t)5242880);
    unsigned short* Xb = (unsigned short*)Yb;
    unsigned short* Ktb = Xb + (size_t)NN * FF;

    k_convA8<<<dim3(16384), dim3(256), 0, stream>>>(A, Ab);
    k_prep<<<dim3(2056), dim3(256), 0, stream>>>(X, Kw, Xb, Ktb);
    k_wx<<<dim3(64, 8), dim3(256), 0, stream>>>(Xb, Ktb, Aw, Vt);
    k_gemm<<<dim3(896), dim3(256), 0, stream>>>(Ab, Vt, Yb);
    k_epi<<<dim3(4096), dim3(256), 0, stream>>>(Yb, out);
}

// Round 10
// 539.948 us; speedup vs baseline: 1.0437x; 1.0437x over previous
//
#include <hip/hip_runtime.h>
#include <cstdint>

// Problem constants
#define NN 8192
#define FF 512
#define FO 64
#define NH 8
#define LDYE 520     // Y row stride: 512 numerator cols + 8 denom cols
#define YPART (8192 * 520)
#define SPLITK 3

// R10 fragment-direct fp8 layouts (no-LDS GEMM). K processed in 64-wide iters.
//  Ab: addr = rt*2^20 + ks*8192 + q*2048 + row*16
//      bytes[0:8)  = A[rt*128+row][ks*64 + q*8 .. +8)      (h2=0 operand)
//      bytes[8:16) = A[rt*128+row][ks*64 + 32 + q*8 .. +8) (h2=1 operand)
//  Vt: addr = ks*40960 + q*10240 + vrow*16, same byte split over node index.
//      vrow: h*64+o (o<64); 512+h = e-row; 520..639 garbage (finite 0xAA).

typedef __attribute__((ext_vector_type(8))) __bf16 bf16x8;
typedef __attribute__((ext_vector_type(4))) float f32x4;
typedef __attribute__((ext_vector_type(2))) long long llx2;

__device__ __forceinline__ unsigned short f2bf(float f) {
    unsigned int u = __float_as_uint(f);
    u += 0x7fffu + ((u >> 16) & 1u);
    return (unsigned short)(u >> 16);
}

__device__ __forceinline__ void gload16(const void* g, void* l) {
    __builtin_amdgcn_global_load_lds(
        (const __attribute__((address_space(1))) unsigned int*)g,
        (__attribute__((address_space(3))) unsigned int*)l,
        16, 0, 0);
}

// ---------------------------------------------------------------------------
// K0: A fp32 {0.0,1.0} -> fp8 e4m3 (0x00/0x38, exact), fragment-direct
// layout. gid = rt*65536 + ks*512 + q*128 + row -> write Ab[gid*16]
// (fully coalesced). Reads: 2x 16B pairs per lane, 256 B burst per A row.
// ---------------------------------------------------------------------------
__global__ __launch_bounds__(256) void k_convA8(const float* __restrict__ A,
                                                unsigned char* __restrict__ Ab) {
    const size_t gid = (size_t)blockIdx.x * 256 + threadIdx.x;
    const int row = (int)(gid & 127);
    const int q   = (int)((gid >> 7) & 3);
    const int ks  = (int)((gid >> 9) & 127);
    const int rt  = (int)(gid >> 16);
    const float* src = A + (((size_t)(rt * 128 + row)) << 13) + ks * 64 + q * 8;
    float4 f0 = *(const float4*)(src);
    float4 f1 = *(const float4*)(src + 4);
    float4 f2 = *(const float4*)(src + 32);
    float4 f3 = *(const float4*)(src + 36);
#define PK8(v) (((v.x >> 22) & 0x38u) | (((v.y >> 22) & 0x38u) << 8) | \
                (((v.z >> 22) & 0x38u) << 16) | (((v.w >> 22) & 0x38u) << 24))
    uint4 fi0 = *(uint4*)&f0, fi1 = *(uint4*)&f1, fi2 = *(uint4*)&f2, fi3 = *(uint4*)&f3;
    uint4 o = {PK8(fi0), PK8(fi1), PK8(fi2), PK8(fi3)};
#undef PK8
    *(uint4*)(Ab + (gid << 4)) = o;
}

// ---------------------------------------------------------------------------
// K0b: X fp32->bf16; kernels (h,f,o)->Kt (h,o,f) bf16.
// ---------------------------------------------------------------------------
__global__ __launch_bounds__(256) void k_prep(const float* __restrict__ X,
                                              const float* __restrict__ Kw,
                                              unsigned short* __restrict__ Xb,
                                              unsigned short* __restrict__ Ktb) {
    const int b = blockIdx.x;
    const int t = threadIdx.x;
    if (b < 2048) {
        size_t base = ((size_t)b * 256 + t) * 8;
        float4 a = *(const float4*)(X + base);
        float4 c = *(const float4*)(X + base + 4);
        ushort4 o0, o1;
        o0.x = f2bf(a.x); o0.y = f2bf(a.y); o0.z = f2bf(a.z); o0.w = f2bf(a.w);
        o1.x = f2bf(c.x); o1.y = f2bf(c.y); o1.z = f2bf(c.z); o1.w = f2bf(c.w);
        *(ushort4*)(Xb + base) = o0;
        *(ushort4*)(Xb + base + 4) = o1;
    } else {
        int h = b - 2048;
        for (int e = t; e < FF * FO; e += 256) {
            int o = e >> 9, f = e & 511;
            Ktb[(size_t)h * FF * FO + e] = f2bf(Kw[(size_t)h * FF * FO + (size_t)f * FO + o]);
        }
    }
}

// ---------------------------------------------------------------------------
// K1: WX = Xb @ Kt^T bf16 MFMA (K=512), s2 via shfl_xor, e = exp(s2),
// emit fp8 V into the fragment-direct Vt layout.
// ---------------------------------------------------------------------------
union WxSmem {
    struct { unsigned short Xs[4096]; unsigned short Ks[2048]; } s;      // 12 KB
    struct { unsigned char Vs[64][144]; unsigned char Es[128]; } r;      // 9.3 KB
};

__global__ __launch_bounds__(256) void k_wx(const unsigned short* __restrict__ Xb,
                                            const unsigned short* __restrict__ Ktb,
                                            const float* __restrict__ Aw,
                                            unsigned char* __restrict__ Vt) {
    __shared__ WxSmem sm;
    const int t = threadIdx.x;
    const int n0 = blockIdx.x * 128;
    const int h = blockIdx.y;
    const int lane = t & 63, w = t >> 6;
    const int quad = lane >> 4, l15 = lane & 15;

    const unsigned short* xS0 = Xb + (size_t)(n0 + (t & 127)) * FF + (t >> 7) * 8;
    const unsigned short* xS1 = Xb + (size_t)(n0 + ((t + 256) & 127)) * FF + ((t + 256) >> 7) * 8;
    unsigned short* xD0 = sm.s.Xs + t * 8;
    unsigned short* xD1 = sm.s.Xs + (t + 256) * 8;
    const unsigned short* kS = Ktb + (size_t)h * FF * FO + (size_t)(t & 63) * FF + (t >> 6) * 8;
    unsigned short* kD = sm.s.Ks + t * 8;

    const bf16x8* aF[2];
    const bf16x8* bF[4];
    for (int i = 0; i < 2; ++i)
        aF[i] = (const bf16x8*)(sm.s.Xs + (size_t)(quad * 128 + w * 32 + i * 16 + l15) * 8);
    for (int j = 0; j < 4; ++j)
        bF[j] = (const bf16x8*)(sm.s.Ks + (size_t)(quad * 64 + j * 16 + l15) * 8);

    f32x4 acc[2][4] = {};
    for (int f0 = 0; f0 < FF; f0 += 32) {
        gload16(xS0 + f0, xD0);
        gload16(xS1 + f0, xD1);
        gload16(kS + f0, kD);
        __syncthreads();
        bf16x8 av[2], bv[4];
        for (int i = 0; i < 2; ++i) av[i] = aF[i][0];
        for (int j = 0; j < 4; ++j) bv[j] = bF[j][0];
        for (int i = 0; i < 2; ++i)
            for (int j = 0; j < 4; ++j)
                acc[i][j] = __builtin_amdgcn_mfma_f32_16x16x32_bf16(av[i], bv[j], acc[i][j], 0, 0, 0);
        __syncthreads();
    }

    float a2v[4];
    for (int j = 0; j < 4; ++j) a2v[j] = Aw[h * 128 + 64 + j * 16 + l15];
    float ex[2][4];
    for (int i = 0; i < 2; ++i)
        for (int r = 0; r < 4; ++r) {
            float p = acc[i][0][r] * a2v[0] + acc[i][1][r] * a2v[1]
                    + acc[i][2][r] * a2v[2] + acc[i][3][r] * a2v[3];
            p += __shfl_xor(p, 1);
            p += __shfl_xor(p, 2);
            p += __shfl_xor(p, 4);
            p += __shfl_xor(p, 8);
            ex[i][r] = __expf(p);
        }

    // fp8 convert + transpose into Vs (o x node); Es = fp8(e) per node
    for (int i = 0; i < 2; ++i)
        for (int j = 0; j < 4; ++j) {
            int rowb = w * 32 + i * 16 + quad * 4;
            int col = j * 16 + l15;
            unsigned u = __builtin_amdgcn_cvt_pk_fp8_f32(
                ex[i][0] * acc[i][j][0], ex[i][1] * acc[i][j][1], 0, false);
            u = __builtin_amdgcn_cvt_pk_fp8_f32(
                ex[i][2] * acc[i][j][2], ex[i][3] * acc[i][j][3], (int)u, true);
            *(unsigned*)&sm.r.Vs[col][rowb] = u;
        }
    if (l15 == 0) {
        for (int i = 0; i < 2; ++i)
            for (int r = 0; r < 4; ++r) {
                int row = w * 32 + i * 16 + quad * 4 + r;
                unsigned u = __builtin_amdgcn_cvt_pk_fp8_f32(ex[i][r], ex[i][r], 0, false);
                sm.r.Es[row] = (unsigned char)(u & 0xff);
            }
    }
    __syncthreads();
    // writeback: 2 ksl x 4 q x 64 o granules = 512 uint4 (2/thread), coalesced
    for (int j2 = 0; j2 < 2; ++j2) {
        int vid = t + j2 * 256;
        int o = vid & 63, q = (vid >> 6) & 3, ksl = vid >> 8;
        const unsigned char* src = &sm.r.Vs[o][ksl * 64 + q * 8];
        uint2 lo = *(const uint2*)src;
        uint2 hi = *(const uint2*)(src + 32);
        uint4 g = {lo.x, lo.y, hi.x, hi.y};
        *(uint4*)(Vt + (size_t)((n0 >> 6) + ksl) * 40960 + q * 10240 + (h * 64 + o) * 16) = g;
    }
    if (t < 8) {  // e-row granules (vrow = 512+h)
        int ksl = t >> 2, q = t & 3;
        uint2 lo = *(const uint2*)&sm.r.Es[ksl * 64 + q * 8];
        uint2 hi = *(const uint2*)&sm.r.Es[ksl * 64 + 32 + q * 8];
        uint4 g = {lo.x, lo.y, hi.x, hi.y};
        *(uint4*)(Vt + (size_t)((n0 >> 6) + ksl) * 40960 + q * 10240 + (512 + h) * 16) = g;
    }
}

// ---------------------------------------------------------------------------
// K2 (R10): BARRIER-FREE register GEMM. Y = A_fp8 @ V^T, fp32 acc.
// BM=128, BN=160, BK=64; 4 waves 2x2, wave tile 64x80 (acc 80 AGPR).
// No LDS: fragments load straight to VGPRs as coalesced dwordx4 (16 B/lane
// = both K-halves). 1-iter register prefetch; no __syncthreads anywhere ->
// compiler emits fine-grained s_waitcnt vmcnt(N>0) and every wave pipelines
// independently (the overlap R8/R9's barriered structures could not express).
// A-fp8 (64 MiB) is L3-resident; XCD swizzle keeps ct-friends' A in one L2.
// ---------------------------------------------------------------------------
__global__ __launch_bounds__(256) void k_gemm(const unsigned char* __restrict__ Ab,
                                              const unsigned char* __restrict__ Vt,
                                              float* __restrict__ Y) {
    const int t = threadIdx.x;
    const int id = blockIdx.x;
    const int xcd = id & 7;
    const int u = id >> 3;                 // 0..95
    const int ct = u & 3;
    const int rp = ((u >> 2) << 3) | xcd;  // 0..191
    const int rt = rp & 63;
    const int part = rp >> 6;              // 0..2
    const int ks0 = (part * 128) / SPLITK;
    const int ks1 = ((part + 1) * 128) / SPLITK;

    const int lane = t & 63;
    const int w = t >> 6;
    const int wm = w >> 1, wn = w & 1;
    const int quad = lane >> 4, l15 = lane & 15;

    // A fragment base: row = wm*64 + i*16 + l15 (i via +256 B imm)
    const unsigned char* aP = Ab + ((size_t)rt << 20) + quad * 2048 + (wm * 64 + l15) * 16;
    // B fragment base: vrow = ct*160 + wn*80 + j*16 + l15 (j via +256 B imm)
    const unsigned char* bP = Vt + quad * 10240 + (ct * 160 + wn * 80 + l15) * 16;

    f32x4 acc[4][5] = {};
    llx2 a_cur[4], b_cur[5];
    {
        const unsigned char* ap = aP + (size_t)ks0 * 8192;
        const unsigned char* bp = bP + (size_t)ks0 * 40960;
        for (int i = 0; i < 4; ++i) a_cur[i] = *(const llx2*)(ap + i * 256);
        for (int j = 0; j < 5; ++j) b_cur[j] = *(const llx2*)(bp + j * 256);
    }

    for (int ks = ks0; ks < ks1; ++ks) {
        const int ksn = (ks + 1 < ks1) ? ks + 1 : ks;
        const unsigned char* ap = aP + (size_t)ksn * 8192;
        const unsigned char* bp = bP + (size_t)ksn * 40960;
        llx2 a_nxt[4], b_nxt[5];
        for (int i = 0; i < 4; ++i) a_nxt[i] = *(const llx2*)(ap + i * 256);
        for (int j = 0; j < 5; ++j) b_nxt[j] = *(const llx2*)(bp + j * 256);
        for (int i = 0; i < 4; ++i)
            for (int j = 0; j < 5; ++j)
                acc[i][j] = __builtin_amdgcn_mfma_f32_16x16x32_fp8_fp8(
                    a_cur[i].x, b_cur[j].x, acc[i][j], 0, 0, 0);
        for (int i = 0; i < 4; ++i)
            for (int j = 0; j < 5; ++j)
                acc[i][j] = __builtin_amdgcn_mfma_f32_16x16x32_fp8_fp8(
                    a_cur[i].y, b_cur[j].y, acc[i][j], 0, 0, 0);
        for (int i = 0; i < 4; ++i) a_cur[i] = a_nxt[i];
        for (int j = 0; j < 5; ++j) b_cur[j] = b_nxt[j];
    }

    // C/D layout: col = lane&15, row = (lane>>4)*4 + reg
    float* Yp = Y + (size_t)part * YPART;
    for (int i = 0; i < 4; ++i) {
        int row = rt * 128 + wm * 64 + i * 16 + quad * 4;
        for (int j = 0; j < 5; ++j) {
            int col = ct * 160 + wn * 80 + j * 16 + l15;
            if (col < 520) {
                for (int r = 0; r < 4; ++r)
                    Yp[(size_t)(row + r) * LDYE + col] = acc[i][j][r];
            }
        }
    }
}

// ---------------------------------------------------------------------------
// K3: out[n, h*64+o] = relu( sum_p Ynum / sum_p Yden )
// ---------------------------------------------------------------------------
__global__ __launch_bounds__(256) void k_epi(const float* __restrict__ Y,
                                             float* __restrict__ out) {
    int idx = blockIdx.x * 256 + threadIdx.x;
    int n = idx >> 7;
    int c = (idx & 127) * 4;
    int h = c >> 6;
    float4 u = {0.f, 0.f, 0.f, 0.f};
    float den = 0.f;
    const float* yp = Y + (size_t)n * LDYE;
#pragma unroll
    for (int p = 0; p < SPLITK; ++p) {
        float4 v = *(const float4*)(yp + c);
        u.x += v.x; u.y += v.y; u.z += v.z; u.w += v.w;
        den += yp[512 + h];
        yp += (size_t)YPART;
    }
    float inv = 1.0f / den;
    float4 o;
    o.x = fmaxf(u.x * inv, 0.f);
    o.y = fmaxf(u.y * inv, 0.f);
    o.z = fmaxf(u.z * inv, 0.f);
    o.w = fmaxf(u.w * inv, 0.f);
    *(float4*)(out + (size_t)n * 512 + c) = o;
}

extern "C" void kernel_launch(void* const* d_in, const int* in_sizes, int n_in,
                              void* d_out, int out_size, void* d_ws, size_t ws_size,
                              hipStream_t stream) {
    const float* X  = (const float*)d_in[0];   // (8192, 512)
    const float* A  = (const float*)d_in[1];   // (8192, 8192)
    const float* Kw = (const float*)d_in[2];   // (8, 512, 64)
    const float* Aw = (const float*)d_in[3];   // (8, 128)
    float* out = (float*)d_out;                // (8192, 512)
    char* ws = (char*)d_ws;
    // ws: Ab 64 MiB | Vt 5 MiB | Yb 3*16.25 MiB (~118 MiB).
    // Xb (8 MiB) + Ktb (0.5 MiB) alias the head of Yb (consumed by k_wx
    // before k_gemm writes Yb).
    unsigned char* Ab = (unsigned char*)ws;
    unsigned char* Vt = (unsigned char*)(ws + (size_t)67108864);
    float* Yb = (float*)(ws + (size_t)67108864 + (size_t)5242880);
    unsigned short* Xb = (unsigned short*)Yb;
    unsigned short* Ktb = Xb + (size_t)NN * FF;

    k_convA8<<<dim3(16384), dim3(256), 0, stream>>>(A, Ab);
    k_prep<<<dim3(2056), dim3(256), 0, stream>>>(X, Kw, Xb, Ktb);
    k_wx<<<dim3(64, 8), dim3(256), 0, stream>>>(Xb, Ktb, Aw, Vt);
    k_gemm<<<dim3(768), dim3(256), 0, stream>>>(Ab, Vt, Yb);
    k_epi<<<dim3(4096), dim3(256), 0, stream>>>(Yb, out);
}

// Round 11
// 508.283 us; speedup vs baseline: 1.1087x; 1.0623x over previous
//
#include <hip/hip_runtime.h>
#include <cstdint>

// Problem constants
#define NN 8192
#define FF 512
#define FO 64
#define NH 8
#define LDYE 520     // Y row stride: 512 numerator cols + 8 denom cols
#define YPART (8192 * 520)
#define SPLITK 3

// Tiled fp8 layouts (k-major 16-byte granules, staging order), R11: BM=64.
//  Ab: granule G = (rt*512 + k16)*64 + row   (rt: 0..127, 64-row stripes)
//  Vt: granule H = k16*640 + vrow   (vrow: h*64+o; 512+h = e-row; >=520 junk)

typedef __attribute__((ext_vector_type(8))) __bf16 bf16x8;
typedef __attribute__((ext_vector_type(4))) float f32x4;

__device__ __forceinline__ unsigned short f2bf(float f) {
    unsigned int u = __float_as_uint(f);
    u += 0x7fffu + ((u >> 16) & 1u);
    return (unsigned short)(u >> 16);
}

__device__ __forceinline__ void gload16(const void* g, void* l) {
    __builtin_amdgcn_global_load_lds(
        (const __attribute__((address_space(1))) unsigned int*)g,
        (__attribute__((address_space(3))) unsigned int*)l,
        16, 0, 0);
}

// ---------------------------------------------------------------------------
// K0: A fp32 {0.0,1.0} -> fp8 e4m3 (0x00/0x38, exact), tiled for BM=64.
// gid = rt*32768 + k16*64 + row -> Ab[gid*16], fully coalesced writes.
// Each lane reads 64 B dense; a block's 256 lanes span 4 k16 x 64 rows, so
// sibling half-lines are consumed in-block.
// ---------------------------------------------------------------------------
__global__ __launch_bounds__(256) void k_convA8(const float* __restrict__ A,
                                                unsigned char* __restrict__ Ab) {
    const size_t gid = (size_t)blockIdx.x * 256 + threadIdx.x;
    const int row = (int)(gid & 63);
    const int k16 = (int)((gid >> 6) & 511);
    const int rt = (int)(gid >> 15);
    const uint4* src = (const uint4*)(A + (((size_t)(rt * 64 + row)) << 13) + k16 * 16);
    uint4 f0 = src[0], f1 = src[1], f2 = src[2], f3 = src[3];
#define PK8(v) (((v.x >> 22) & 0x38u) | (((v.y >> 22) & 0x38u) << 8) | \
                (((v.z >> 22) & 0x38u) << 16) | (((v.w >> 22) & 0x38u) << 24))
    uint4 o = {PK8(f0), PK8(f1), PK8(f2), PK8(f3)};
#undef PK8
    *(uint4*)(Ab + (gid << 4)) = o;
}

// ---------------------------------------------------------------------------
// K0b: X fp32->bf16; kernels (h,f,o)->Kt (h,o,f) bf16.
// ---------------------------------------------------------------------------
__global__ __launch_bounds__(256) void k_prep(const float* __restrict__ X,
                                              const float* __restrict__ Kw,
                                              unsigned short* __restrict__ Xb,
                                              unsigned short* __restrict__ Ktb) {
    const int b = blockIdx.x;
    const int t = threadIdx.x;
    if (b < 2048) {
        size_t base = ((size_t)b * 256 + t) * 8;
        float4 a = *(const float4*)(X + base);
        float4 c = *(const float4*)(X + base + 4);
        ushort4 o0, o1;
        o0.x = f2bf(a.x); o0.y = f2bf(a.y); o0.z = f2bf(a.z); o0.w = f2bf(a.w);
        o1.x = f2bf(c.x); o1.y = f2bf(c.y); o1.z = f2bf(c.z); o1.w = f2bf(c.w);
        *(ushort4*)(Xb + base) = o0;
        *(ushort4*)(Xb + base + 4) = o1;
    } else {
        int h = b - 2048;
        for (int e = t; e < FF * FO; e += 256) {
            int o = e >> 9, f = e & 511;
            Ktb[(size_t)h * FF * FO + e] = f2bf(Kw[(size_t)h * FF * FO + (size_t)f * FO + o]);
        }
    }
}

// ---------------------------------------------------------------------------
// K1: WX = Xb @ Kt^T bf16 MFMA (K=512), s2 via shfl_xor, e = exp(s2),
// emit fp8 V into tiled Vt (k16-granule layout). Verbatim R7 (512 µs best).
// ---------------------------------------------------------------------------
union WxSmem {
    struct { unsigned short Xs[4096]; unsigned short Ks[2048]; } s;
    unsigned char Vs[64][144];
};

__global__ __launch_bounds__(256) void k_wx(const unsigned short* __restrict__ Xb,
                                            const unsigned short* __restrict__ Ktb,
                                            const float* __restrict__ Aw,
                                            unsigned char* __restrict__ Vt) {
    __shared__ WxSmem sm;
    const int t = threadIdx.x;
    const int n0 = blockIdx.x * 128;
    const int h = blockIdx.y;
    const int lane = t & 63, w = t >> 6;
    const int quad = lane >> 4, l15 = lane & 15;

    const unsigned short* xS0 = Xb + (size_t)(n0 + (t & 127)) * FF + (t >> 7) * 8;
    const unsigned short* xS1 = Xb + (size_t)(n0 + ((t + 256) & 127)) * FF + ((t + 256) >> 7) * 8;
    unsigned short* xD0 = sm.s.Xs + t * 8;
    unsigned short* xD1 = sm.s.Xs + (t + 256) * 8;
    const unsigned short* kS = Ktb + (size_t)h * FF * FO + (size_t)(t & 63) * FF + (t >> 6) * 8;
    unsigned short* kD = sm.s.Ks + t * 8;

    const bf16x8* aF[2];
    const bf16x8* bF[4];
    for (int i = 0; i < 2; ++i)
        aF[i] = (const bf16x8*)(sm.s.Xs + (size_t)(quad * 128 + w * 32 + i * 16 + l15) * 8);
    for (int j = 0; j < 4; ++j)
        bF[j] = (const bf16x8*)(sm.s.Ks + (size_t)(quad * 64 + j * 16 + l15) * 8);

    f32x4 acc[2][4] = {};
    for (int f0 = 0; f0 < FF; f0 += 32) {
        gload16(xS0 + f0, xD0);
        gload16(xS1 + f0, xD1);
        gload16(kS + f0, kD);
        __syncthreads();
        bf16x8 av[2], bv[4];
        for (int i = 0; i < 2; ++i) av[i] = aF[i][0];
        for (int j = 0; j < 4; ++j) bv[j] = bF[j][0];
        for (int i = 0; i < 2; ++i)
            for (int j = 0; j < 4; ++j)
                acc[i][j] = __builtin_amdgcn_mfma_f32_16x16x32_bf16(av[i], bv[j], acc[i][j], 0, 0, 0);
        __syncthreads();
    }

    float a2v[4];
    for (int j = 0; j < 4; ++j) a2v[j] = Aw[h * 128 + 64 + j * 16 + l15];
    float ex[2][4];
    for (int i = 0; i < 2; ++i)
        for (int r = 0; r < 4; ++r) {
            float p = acc[i][0][r] * a2v[0] + acc[i][1][r] * a2v[1]
                    + acc[i][2][r] * a2v[2] + acc[i][3][r] * a2v[3];
            p += __shfl_xor(p, 1);
            p += __shfl_xor(p, 2);
            p += __shfl_xor(p, 4);
            p += __shfl_xor(p, 8);
            ex[i][r] = __expf(p);
        }

    for (int i = 0; i < 2; ++i)
        for (int j = 0; j < 4; ++j) {
            int rowb = w * 32 + i * 16 + quad * 4;
            int col = j * 16 + l15;
            unsigned u = __builtin_amdgcn_cvt_pk_fp8_f32(
                ex[i][0] * acc[i][j][0], ex[i][1] * acc[i][j][1], 0, false);
            u = __builtin_amdgcn_cvt_pk_fp8_f32(
                ex[i][2] * acc[i][j][2], ex[i][3] * acc[i][j][3], (int)u, true);
            *(unsigned*)&sm.Vs[col][rowb] = u;
        }
    __syncthreads();
    for (int j2 = 0; j2 < 2; ++j2) {
        int vid = t + j2 * 256;            // 0..511 = 64 o x 8 k16o (uint4)
        int o = vid >> 3, k16o = vid & 7;
        size_t H = (size_t)((n0 >> 4) + k16o) * 640 + h * 64 + o;
        *(uint4*)(Vt + (H << 4)) = *(const uint4*)&sm.Vs[o][k16o * 16];
    }
    if (l15 == 0) {
        for (int i = 0; i < 2; ++i)
            for (int r = 0; r < 4; ++r) {
                int row = w * 32 + i * 16 + quad * 4 + r;
                unsigned u = __builtin_amdgcn_cvt_pk_fp8_f32(ex[i][r], ex[i][r], 0, false);
                size_t H = (size_t)((n0 >> 4) + (row >> 4)) * 640 + 512 + h;
                Vt[(H << 4) + (row & 15)] = (unsigned char)(u & 0xff);
            }
    }
}

// ---------------------------------------------------------------------------
// K2 (R11): R7's single-buffered 2-barrier loop, BM 128->64 for OCCUPANCY.
// BM=64, BN=160, BK=64; wave tile 32x80 -> acc 40 AGPR, ~80 regs total
// (__launch_bounds__(256,5) caps at ~102) -> 5 waves/SIMD vs 3.
// LDS 14 KB. Grid 128x4x3 = 1536 = 6 blocks/CU -> ~5 resident (~60% occ),
// doubling cross-wave latency hiding of the same barrier drain.
// A tile = 4 KB = exactly ONE gload16/iter; B = 2.5.
// XCD swizzle keeps the 4 ct-friends of each A stripe on one XCD.
// ---------------------------------------------------------------------------
__global__ __launch_bounds__(256, 5) void k_gemm(const unsigned char* __restrict__ Ab,
                                                 const unsigned char* __restrict__ Vt,
                                                 float* __restrict__ Y) {
    __shared__ unsigned char As[4096];    // kq(4) x row(64) x 16 B
    __shared__ unsigned char Bs[10240];   // kq(4) x n(160) x 16 B
    const int t = threadIdx.x;
    const int id = blockIdx.x;
    const int xcd = id & 7;
    const int u = id >> 3;                 // 0..191
    const int ct = u & 3;
    const int rp = ((u >> 2) << 3) | xcd;  // 0..383
    const int rt = rp & 127;               // 0..127
    const int part = rp >> 7;              // 0..2
    const int ks0 = (part * 128) / SPLITK; // 128 iters of BK=64 total
    const int ks1 = ((part + 1) * 128) / SPLITK;

    // A staging: one gload16 covers the whole 4 KB tile (granule g = t).
    const unsigned char* aS = Ab + ((size_t)rt << 19) + (size_t)t * 16;
    unsigned char* aD = As + t * 16;
    // B staging: granule g = t + 256j; source = (g/160)*10240 + (ct*160+g%160)*16.
    const int g1 = t + 256, g2 = t + 512;
    const unsigned char* bS0 = Vt + (size_t)((t / 160) * 10240 + (ct * 160 + t % 160) * 16);
    const unsigned char* bS1 = Vt + (size_t)((g1 / 160) * 10240 + (ct * 160 + g1 % 160) * 16);
    const unsigned char* bS2 = Vt + (size_t)((g2 / 160) * 10240 + (ct * 160 + g2 % 160) * 16);
    unsigned char* bD0 = Bs + t * 16;
    unsigned char* bD1 = Bs + g1 * 16;
    unsigned char* bD2 = Bs + g2 * 16;

    const int lane = t & 63;
    const int w = t >> 6;
    const int wm = w >> 1, wn = w & 1;
    const int quad = lane >> 4, l15 = lane & 15;

    // fragment byte offsets (h2=0): A h2=1 adds 2048, B h2=1 adds 5120
    int aOff[2], bOff[5];
    for (int i = 0; i < 2; ++i)
        aOff[i] = (quad >> 1) * 1024 + (quad & 1) * 8 + (wm * 32 + i * 16 + l15) * 16;
    for (int j = 0; j < 5; ++j)
        bOff[j] = (quad >> 1) * 2560 + (quad & 1) * 8 + (wn * 80 + j * 16 + l15) * 16;

    f32x4 acc[2][5] = {};

    for (int ks = ks0; ks < ks1; ++ks) {
        const size_t koA = (size_t)ks << 12;       // *4096
        const size_t koB = (size_t)ks * 40960;
        gload16(aS + koA, aD);
        gload16(bS0 + koB, bD0);
        gload16(bS1 + koB, bD1);
        if (t < 128) gload16(bS2 + koB, bD2);
        __syncthreads();
#pragma unroll
        for (int h2 = 0; h2 < 2; ++h2) {
            long long av[2], bv[5];
            for (int i = 0; i < 2; ++i)
                av[i] = *(const long long*)(As + aOff[i] + h2 * 2048);
            for (int j = 0; j < 5; ++j)
                bv[j] = *(const long long*)(Bs + bOff[j] + h2 * 5120);
            for (int i = 0; i < 2; ++i)
                for (int j = 0; j < 5; ++j)
                    acc[i][j] = __builtin_amdgcn_mfma_f32_16x16x32_fp8_fp8(
                        av[i], bv[j], acc[i][j], 0, 0, 0);
        }
        __syncthreads();
    }

    // C/D layout: col = lane&15, row = (lane>>4)*4 + reg
    float* Yp = Y + (size_t)part * YPART;
    for (int i = 0; i < 2; ++i) {
        int row = rt * 64 + wm * 32 + i * 16 + quad * 4;
        for (int j = 0; j < 5; ++j) {
            int col = ct * 160 + wn * 80 + j * 16 + l15;
            if (col < 520) {
                for (int r = 0; r < 4; ++r)
                    Yp[(size_t)(row + r) * LDYE + col] = acc[i][j][r];
            }
        }
    }
}

// ---------------------------------------------------------------------------
// K3: out[n, h*64+o] = relu( sum_p Ynum / sum_p Yden )
// ---------------------------------------------------------------------------
__global__ __launch_bounds__(256) void k_epi(const float* __restrict__ Y,
                                             float* __restrict__ out) {
    int idx = blockIdx.x * 256 + threadIdx.x;
    int n = idx >> 7;
    int c = (idx & 127) * 4;
    int h = c >> 6;
    float4 u = {0.f, 0.f, 0.f, 0.f};
    float den = 0.f;
    const float* yp = Y + (size_t)n * LDYE;
#pragma unroll
    for (int p = 0; p < SPLITK; ++p) {
        float4 v = *(const float4*)(yp + c);
        u.x += v.x; u.y += v.y; u.z += v.z; u.w += v.w;
        den += yp[512 + h];
        yp += (size_t)YPART;
    }
    float inv = 1.0f / den;
    float4 o;
    o.x = fmaxf(u.x * inv, 0.f);
    o.y = fmaxf(u.y * inv, 0.f);
    o.z = fmaxf(u.z * inv, 0.f);
    o.w = fmaxf(u.w * inv, 0.f);
    *(float4*)(out + (size_t)n * 512 + c) = o;
}

extern "C" void kernel_launch(void* const* d_in, const int* in_sizes, int n_in,
                              void* d_out, int out_size, void* d_ws, size_t ws_size,
                              hipStream_t stream) {
    const float* X  = (const float*)d_in[0];   // (8192, 512)
    const float* A  = (const float*)d_in[1];   // (8192, 8192)
    const float* Kw = (const float*)d_in[2];   // (8, 512, 64)
    const float* Aw = (const float*)d_in[3];   // (8, 128)
    float* out = (float*)d_out;                // (8192, 512)
    char* ws = (char*)d_ws;
    // ws: Ab 64 MiB | Vt 5 MiB | Yb 3*16.25 MiB (~118 MiB).
    // Xb (8 MiB) + Ktb (0.5 MiB) alias the head of Yb (consumed by k_wx
    // before k_gemm writes Yb).
    unsigned char* Ab = (unsigned char*)ws;
    unsigned char* Vt = (unsigned char*)(ws + (size_t)67108864);
    float* Yb = (float*)(ws + (size_t)67108864 + (size_t)5242880);
    unsigned short* Xb = (unsigned short*)Yb;
    unsigned short* Ktb = Xb + (size_t)NN * FF;

    k_convA8<<<dim3(16384), dim3(256), 0, stream>>>(A, Ab);
    k_prep<<<dim3(2056), dim3(256), 0, stream>>>(X, Kw, Xb, Ktb);
    k_wx<<<dim3(64, 8), dim3(256), 0, stream>>>(Xb, Ktb, Aw, Vt);
    k_gemm<<<dim3(1536), dim3(256), 0, stream>>>(Ab, Vt, Yb);
    k_epi<<<dim3(4096), dim3(256), 0, stream>>>(Yb, out);
}